// Round 16
// baseline (225.135 us; speedup 1.0000x reference)
//
#include <hip/hip_runtime.h>
#include <hip/hip_bf16.h>
#include <math.h>

namespace {
constexpr int M  = 48;    // fields
constexpr int D  = 128;   // embedding dim
constexpr int DH = 64;    // d's per block (d-half)
constexpr int H1 = 68;
constexpr int H2 = 32;
constexpr int H3 = 24;
constexpr int PO = H1 + H2 + H3;  // 124
constexpr int K1 = M  * M;   // 2304
constexpr int K2 = H1 * M;   // 3264
constexpr int K3 = H2 * M;   // 1536
constexpr int HOP1 = 96;     // H1 padded to 3 N-tiles of 32
constexpr int HOP2 = 32;
constexpr int HOP3 = 32;
// ws layout (ushort elements for weights, then float arrays)
constexpr int E1 = (K1 / 8) * HOP1 * 8;   // 221184
constexpr int E2 = (K2 / 8) * HOP2 * 8;   // 104448
constexpr int E3 = (K3 / 8) * HOP3 * 8;   //  49152
constexpr int EF = (M * D) * 64;          // 393216  fc1_w bf16
constexpr int EW = E1 + E2 + E3 + EF;     // 768000 ushorts
// float region offsets (in floats, from wsf base)
constexpr int OPOOL = 0;                  // ppool[1024][128], slot = b*2+h
constexpr int OH1P  = 1024 * 128;         // h1p[1024][64]
constexpr int X0S = 56;  // x0h f16 stride (112 B rows -> 16B-aligned half8 loads)
constexpr int BAS = 69;  // bufA f16 stride
constexpr int BBS = 33;  // bufB f16 stride
constexpr int DHX = DH * X0S, DHA = DH * BAS, DHB = DH * BBS;
constexpr float BN_SCALE = 0.9995003746877732f;  // 1/sqrt(1+1e-3)
// prep thread-space
constexpr int P1 = (K1 / 8) * HOP1;  // 27648
constexpr int P2 = (K2 / 8) * HOP2;  // 13056
constexpr int P3 = (K3 / 8) * HOP3;  //  6144
constexpr int P4 = EF / 8;           // 49152
}

typedef __attribute__((ext_vector_type(8)))  _Float16 half8;
typedef __attribute__((ext_vector_type(16))) float f32x16;
typedef __attribute__((ext_vector_type(8)))  unsigned short us8;

static __device__ __forceinline__ unsigned short f2bs(float f) {  // bf16 RNE (fc1 path)
    __hip_bfloat16 h = __float2bfloat16(f);
    return __builtin_bit_cast(unsigned short, h);
}
static __device__ __forceinline__ unsigned short f2hs(float f) {  // f16 RNE
    _Float16 h = (_Float16)f;
    return __builtin_bit_cast(unsigned short, h);
}
static __device__ __forceinline__ float hs2f(unsigned short u) {  // f16 -> f32
    return (float)__builtin_bit_cast(_Float16, u);
}

// ---------------- prep: transpose+convert weights into d_ws ------------------
__global__ __launch_bounds__(256)
void prep_kernel(const float* __restrict__ w1, const float* __restrict__ w2,
                 const float* __restrict__ w3, const float* __restrict__ fc1w,
                 unsigned short* __restrict__ ws)
{
    const int tid = blockIdx.x * 256 + threadIdx.x;
    us8 v;
    if (tid < P1) {
        const int k8 = tid / HOP1, o = tid - k8 * HOP1;
        #pragma unroll
        for (int i = 0; i < 8; ++i)
            v[i] = (o < H1) ? f2hs(w1[(k8 * 8 + i) * H1 + o]) : (unsigned short)0;
        *(uint4*)(ws + (size_t)k8 * (HOP1 * 8) + o * 8) = __builtin_bit_cast(uint4, v);
    } else if (tid < P1 + P2) {
        const int x = tid - P1;
        const int k8 = x >> 5, o = x & 31;
        #pragma unroll
        for (int i = 0; i < 8; ++i)
            v[i] = f2hs(w2[(k8 * 8 + i) * H2 + o]);
        *(uint4*)(ws + E1 + (size_t)k8 * (HOP2 * 8) + o * 8) = __builtin_bit_cast(uint4, v);
    } else if (tid < P1 + P2 + P3) {
        const int x = tid - (P1 + P2);
        const int k8 = x >> 5, o = x & 31;
        #pragma unroll
        for (int i = 0; i < 8; ++i)
            v[i] = (o < H3) ? f2hs(w3[(k8 * 8 + i) * H3 + o]) : (unsigned short)0;
        *(uint4*)(ws + E1 + E2 + (size_t)k8 * (HOP3 * 8) + o * 8) = __builtin_bit_cast(uint4, v);
    } else if (tid < P1 + P2 + P3 + P4) {
        const int x = tid - (P1 + P2 + P3);
        const float4 a = ((const float4*)fc1w)[x * 2];
        const float4 b = ((const float4*)fc1w)[x * 2 + 1];
        v[0] = f2bs(a.x); v[1] = f2bs(a.y); v[2] = f2bs(a.z); v[3] = f2bs(a.w);
        v[4] = f2bs(b.x); v[5] = f2bs(b.y); v[6] = f2bs(b.z); v[7] = f2bs(b.w);
        *(uint4*)(ws + E1 + E2 + E3 + (size_t)x * 8) = __builtin_bit_cast(uint4, v);
    }
}

// ---------------- CIN layer, batch-PAIR, 32x32x16 f16 MFMA -------------------
// Block = (b-pair, d-half). Each B-fragment load feeds TWO MFMAs (rows bb=0,1)
// -> 2x arithmetic per B byte; prefetch distance 3 now holds ~2*NT*3*32 cyc of
// MFMA work in flight per wave. 4 waves = (tile 2) x (khalf 2); khalf combine
// store->barrier->add. A-build: 4 v_pk_mul_f16 per row.
// NO device-scope fences (per-XCD L2 writeback — R10 regression).
template<int KTOT, int HO, int NT, int HOP, bool WRITEBUF>
__device__ __forceinline__ void cin_mfma(
    const unsigned short* __restrict__ x0a, const unsigned short* __restrict__ x0b,
    const unsigned short* __restrict__ xka, const unsigned short* __restrict__ xkb,
    int xkstride,
    const unsigned short* __restrict__ wt,
    unsigned short* __restrict__ oa, unsigned short* __restrict__ ob, int outstride,
    float* __restrict__ pla, float* __restrict__ plb, int poff, int t)
{
    const int lane  = t & 63;
    const int w     = t >> 6;
    const int tile  = w & 1;
    const int khalf = w >> 1;
    const int o0 = lane & 31, h2 = lane >> 5;
    const int dl = tile * 32 + o0;          // this lane's A-row (local d)
    constexpr int KS = KTOT / 16;
    constexpr int KH = KS / 2;
    static_assert(KH % 6 == 0, "K-half must be a multiple of 6 ksteps");
    const int ks0 = khalf * KH;
    const int kb0 = ks0 / 3;

    // x0 j-operands: 3 fixed half8 registers per row for the whole layer
    half8 qA[3], qB[3];
    #pragma unroll
    for (int p = 0; p < 3; ++p) {
        qA[p] = *(const half8*)(x0a + dl * X0S + (2 * p + h2) * 8);
        qB[p] = *(const half8*)(x0b + dl * X0S + (2 * p + h2) * 8);
    }

    f32x16 accA[NT], accB[NT];
    #pragma unroll
    for (int nt = 0; nt < NT; ++nt)
        #pragma unroll
        for (int r = 0; r < 16; ++r) { accA[nt][r] = 0.f; accB[nt][r] = 0.f; }

    const unsigned short* xrA = xka + dl * xkstride;
    const unsigned short* xrB = xkb + dl * xkstride;
    const unsigned short* wb = wt + (size_t)(h2 * HOP + o0) * 8;

    auto xsplat = [&](const unsigned short* xr, int k) -> half8 {
        const unsigned int xp = (unsigned int)xr[k] * 0x10001u;
        uint4 s; s.x = xp; s.y = xp; s.z = xp; s.w = xp;
        return __builtin_bit_cast(half8, s);
    };

    uint4 br[3][NT];
    auto loadB = [&](int ks, uint4* b) {
        const unsigned short* p = wb + (size_t)ks * (2 * HOP * 8);
        #pragma unroll
        for (int nt = 0; nt < NT; ++nt)
            b[nt] = *(const uint4*)(p + nt * 256);
    };
    auto phase = [&](int p, half8 xa, half8 xb, const uint4* b) {
        const half8 avA = xa * qA[p];         // 4 v_pk_mul_f16
        const half8 avB = xb * qB[p];
        #pragma unroll
        for (int nt = 0; nt < NT; ++nt) {
            const half8 bv = __builtin_bit_cast(half8, b[nt]);
            accA[nt] = __builtin_amdgcn_mfma_f32_32x32x16_f16(avA, bv, accA[nt], 0, 0, 0);
            accB[nt] = __builtin_amdgcn_mfma_f32_32x32x16_f16(avB, bv, accB[nt], 0, 0, 0);
        }
    };

    loadB(ks0 + 0, br[0]);
    loadB(ks0 + 1, br[1]);
    loadB(ks0 + 2, br[2]);
    half8 xa0 = xsplat(xrA, kb0), xb0 = xsplat(xrB, kb0);
    #pragma unroll 1
    for (int it = 0; it < KH / 6; ++it) {
        const int g  = ks0 + it * 6;
        const int kb = kb0 + it * 2;
        const half8 xa1 = xsplat(xrA, kb + 1), xb1 = xsplat(xrB, kb + 1);
        phase(0, xa0, xb0, br[0]);  loadB(g + 3, br[0]);
        phase(1, xa0, xb0, br[1]);  loadB(g + 4, br[1]);
        phase(2, xa0, xb0, br[2]);  loadB(g + 5, br[2]);
        const half8 xan = xsplat(xrA, kb + 2), xbn = xsplat(xrB, kb + 2);  // in-pad last iter
        phase(0, xa1, xb1, br[0]);  loadB(g + 6, br[0]);
        phase(1, xa1, xb1, br[1]);  loadB(g + 7, br[1]);   // tail loads stay inside d_ws
        phase(2, xa1, xb1, br[2]);  loadB(g + 8, br[2]);
        xa0 = xan; xb0 = xbn;
    }

    // epilogue: pool partials + khalf=0 stores (f16), barrier, khalf=1 adds
    const int dbase = tile * 32 + 4 * h2;
    #pragma unroll
    for (int nt = 0; nt < NT; ++nt) {
        const int o = nt * 32 + o0;
        if (o < HO) {
            float sa = 0.f, sb = 0.f;
            #pragma unroll
            for (int r = 0; r < 16; ++r) { sa += accA[nt][r]; sb += accB[nt][r]; }
            if (WRITEBUF && khalf == 0) {
                #pragma unroll
                for (int r = 0; r < 16; ++r) {
                    const int idx = (dbase + (r & 3) + 8 * (r >> 2)) * outstride + o;
                    oa[idx] = f2hs(accA[nt][r]);
                    ob[idx] = f2hs(accB[nt][r]);
                }
            }
            sa += __shfl_xor(sa, 32, 64);
            sb += __shfl_xor(sb, 32, 64);
            if (lane < 32) {
                atomicAdd(&pla[poff + o], sa);
                atomicAdd(&plb[poff + o], sb);
            }
        }
    }
    if (WRITEBUF) {
        __syncthreads();                  // khalf=0 partials visible
        if (khalf == 1) {
            #pragma unroll
            for (int nt = 0; nt < NT; ++nt) {
                const int o = nt * 32 + o0;
                if (o < HO) {
                    #pragma unroll
                    for (int r = 0; r < 16; ++r) {
                        const int idx = (dbase + (r & 3) + 8 * (r >> 2)) * outstride + o;
                        oa[idx] = f2hs(hs2f(oa[idx]) + accA[nt][r]);
                        ob[idx] = f2hs(hs2f(ob[idx]) + accB[nt][r]);
                    }
                }
            }
        }
        __syncthreads();                  // combined bufs visible to next layer
    }
}

__global__ __launch_bounds__(256, 2)
void dcin_kernel(const int*   __restrict__ x,
                 const float* __restrict__ emb,
                 const unsigned short* __restrict__ ws,   // f16/bf16 weights
                 float* __restrict__ wsf)                 // float partial region
{
    __shared__ __align__(16) unsigned short x0h [2 * DHX];   // 14336 B f16 embeds
    __shared__ __align__(16) unsigned short bufA[2 * DHA];   // 17664 B f16 L1 out
    __shared__ __align__(16) unsigned short bufB[2 * DHB];   //  8448 B f16 L2 out
    __shared__ float pool_s[2 * PO];                         //   992 B
    __shared__ int   sx[2 * M];                              //   384 B
    float* const red2 = (float*)bufB;    // 512 floats (2048B <= 8448B), after layer 3

    const unsigned short* wt1  = ws;
    const unsigned short* wt2  = ws + E1;
    const unsigned short* wt3  = ws + E1 + E2;
    const unsigned short* fc1b = ws + E1 + E2 + E3;

    const int pair = blockIdx.x >> 1;
    const int h    = blockIdx.x & 1;   // d-half
    const int b0   = pair * 2;
    const int t    = threadIdx.x;

    if (t < 2 * M) sx[t] = x[(b0 + t / M) * M + (t % M)];
    if (t < 2 * PO) pool_s[t] = 0.f;
    __syncthreads();

    // gather x0h[bb][dl][j] = f16(emb[sx[bb][j]][h*64+dl]); j-fast writes
    for (int i = t; i < 2 * M * (DH / 4); i += 256) {
        const int bb = i / (M * (DH / 4));
        const int r  = i - bb * (M * (DH / 4));
        const int c  = r / 48;
        const int j  = r - c * 48;
        const float4 v = ((const float4*)(emb + (size_t)sx[bb * M + j] * D))[h * 16 + c];
        unsigned short* xx = x0h + bb * DHX;
        xx[(4 * c + 0) * X0S + j] = f2hs(v.x);
        xx[(4 * c + 1) * X0S + j] = f2hs(v.y);
        xx[(4 * c + 2) * X0S + j] = f2hs(v.z);
        xx[(4 * c + 3) * X0S + j] = f2hs(v.w);
    }
    __syncthreads();

    // ---- CIN layers (batch-pair 32x32x16 f16 MFMA) ----
    cin_mfma<K1, H1, 3, HOP1, true >(x0h, x0h + DHX, x0h, x0h + DHX, X0S, wt1,
                                     bufA, bufA + DHA, BAS, pool_s, pool_s + PO, 0, t);
    cin_mfma<K2, H2, 1, HOP2, true >(x0h, x0h + DHX, bufA, bufA + DHA, BAS, wt2,
                                     bufB, bufB + DHB, BBS, pool_s, pool_s + PO, H1, t);
    cin_mfma<K3, H3, 1, HOP3, false>(x0h, x0h + DHX, bufB, bufB + DHB, BBS, wt3,
                                     nullptr, nullptr, 0, pool_s, pool_s + PO, H1 + H2, t);
    __syncthreads();   // pool complete, bufB (red2 alias) dead

    // ---- fc1 partials for both rows (bf16 weights, f16 x0), no bias/act ----
    {
        const int bb   = t >> 7;          // 0..1: which batch row
        const int u2   = (t & 31) * 2;
        const int part = (t >> 5) & 3;    // 4 parts x 12 fields
        const unsigned short* xb = x0h + bb * DHX;
        float a0 = 0.f, a1 = 0.f;
        for (int j = part * 12; j < part * 12 + 12; ++j) {
            const unsigned short* xr = xb + j;
            #pragma unroll 4
            for (int d = 0; d < DH; ++d) {
                const float xv = hs2f(xr[d * X0S]);
                const unsigned int wp = *(const unsigned int*)(
                    fc1b + (size_t)(j * D + h * DH + d) * 64 + u2);
                a0 = fmaf(xv, __builtin_bit_cast(float, wp << 16), a0);
                a1 = fmaf(xv, __builtin_bit_cast(float, wp & 0xffff0000u), a1);
            }
        }
        red2[bb * 256 + (part * 32 + (t & 31)) * 2]     = a0;
        red2[bb * 256 + (part * 32 + (t & 31)) * 2 + 1] = a1;
    }
    __syncthreads();

    // ---- store partials to global (slot = b*2 + h, unchanged layout) ----
    if (t < 128) {
        const int bb = t >> 6, u = t & 63;
        float v = 0.f;
        #pragma unroll
        for (int p = 0; p < 4; ++p)
            v += red2[bb * 256 + (p * 32 + (u >> 1)) * 2 + (u & 1)];
        wsf[OH1P + ((size_t)(b0 + bb) * 2 + h) * 64 + u] = v;
    }
    for (int i = t; i < 2 * PO; i += 256) {
        const int bb = i / PO, idx = i - bb * PO;
        wsf[OPOOL + ((size_t)(b0 + bb) * 2 + h) * 128 + idx] = pool_s[i];
    }
}

// ---------------- tail: combine halves + fc chain + output -------------------
__global__ __launch_bounds__(64)
void tail_kernel(const int*   __restrict__ x,
                 const float* __restrict__ lin_w, const float* __restrict__ lin_b,
                 const float* __restrict__ fc1_b,
                 const float* __restrict__ bn1_g, const float* __restrict__ bn1_b,
                 const float* __restrict__ fc2_w, const float* __restrict__ fc2_b,
                 const float* __restrict__ bn2_g, const float* __restrict__ bn2_b,
                 const float* __restrict__ fc3_w, const float* __restrict__ fc3_b,
                 const float* __restrict__ bn3_g, const float* __restrict__ bn3_b,
                 const float* __restrict__ out_w, const float* __restrict__ out_b,
                 const float* __restrict__ wsf,
                 float* __restrict__ out)
{
    __shared__ float h1s[64], h2s[48], h3s[24];
    __shared__ float pool_s[PO];
    const int b = blockIdx.x;
    const int t = threadIdx.x;
    const int s0 = b * 2, s1 = b * 2 + 1;

    {
        float v = wsf[OH1P + s0 * 64 + t] + wsf[OH1P + s1 * 64 + t] + fc1_b[t];
        v = fmaxf(v, 0.f);
        h1s[t] = bn1_g[t] * v * BN_SCALE + bn1_b[t];
    }
    for (int i = t; i < PO; i += 64)
        pool_s[i] = wsf[OPOOL + s0 * 128 + i] + wsf[OPOOL + s1 * 128 + i];
    __syncthreads();

    if (t < 48) {
        float a = fc2_b[t];
        #pragma unroll 4
        for (int u = 0; u < 64; ++u) a = fmaf(h1s[u], fc2_w[u * 48 + t], a);
        a = tanhf(a);
        h2s[t] = bn2_g[t] * a * BN_SCALE + bn2_b[t];
    }
    __syncthreads();

    if (t < 24) {
        float a = fc3_b[t];
        #pragma unroll 4
        for (int u = 0; u < 48; ++u) a = fmaf(h2s[u], fc3_w[u * 24 + t], a);
        a = tanhf(a);
        h3s[t] = bn3_g[t] * a * BN_SCALE + bn3_b[t];
    }
    __syncthreads();

    if (t == 0) {
        float s = lin_b[0];
        for (int j = 0; j < M; ++j) s += (float)x[b * M + j] * lin_w[j];
        const float slin = tanhf(s);
        float z = out_b[0];
        #pragma unroll 4
        for (int i = 0; i < H3; ++i) z = fmaf(h3s[i], out_w[i], z);
        z = fmaf(slin, out_w[H3], z);
        #pragma unroll 4
        for (int i = 0; i < PO; ++i)
            z = fmaf(pool_s[i], out_w[H3 + 1 + i], z);
        out[b] = 1.f / (1.f + expf(-z));
    }
}

extern "C" void kernel_launch(void* const* d_in, const int* in_sizes, int n_in,
                              void* d_out, int out_size, void* d_ws, size_t ws_size,
                              hipStream_t stream) {
    (void)in_sizes; (void)n_in; (void)ws_size; (void)out_size;
    const int*   x     = (const int*)  d_in[0];
    const float* emb   = (const float*)d_in[1];
    const float* w1    = (const float*)d_in[2];
    const float* w2    = (const float*)d_in[3];
    const float* w3    = (const float*)d_in[4];
    const float* lin_w = (const float*)d_in[5];
    const float* lin_b = (const float*)d_in[6];
    const float* fc1_w = (const float*)d_in[7];
    const float* fc1_b = (const float*)d_in[8];
    const float* bn1_g = (const float*)d_in[9];
    const float* bn1_b = (const float*)d_in[10];
    const float* fc2_w = (const float*)d_in[11];
    const float* fc2_b = (const float*)d_in[12];
    const float* bn2_g = (const float*)d_in[13];
    const float* bn2_b = (const float*)d_in[14];
    const float* fc3_w = (const float*)d_in[15];
    const float* fc3_b = (const float*)d_in[16];
    const float* bn3_g = (const float*)d_in[17];
    const float* bn3_b = (const float*)d_in[18];
    const float* out_w = (const float*)d_in[19];
    const float* out_b = (const float*)d_in[20];
    unsigned short* ws = (unsigned short*)d_ws;
    float* wsf = (float*)(ws + EW);

    const int prep_threads = P1 + P2 + P3 + P4;
    prep_kernel<<<(prep_threads + 255) / 256, 256, 0, stream>>>(w1, w2, w3, fc1_w, ws);

    dcin_kernel<<<512, 256, 0, stream>>>(x, emb, ws, wsf);

    tail_kernel<<<512, 64, 0, stream>>>(
        x, lin_w, lin_b, fc1_b, bn1_g, bn1_b,
        fc2_w, fc2_b, bn2_g, bn2_b,
        fc3_w, fc3_b, bn3_g, bn3_b,
        out_w, out_b, wsf, (float*)d_out);
}

// Round 17
// 195.328 us; speedup vs baseline: 1.1526x; 1.1526x over previous
//
#include <hip/hip_runtime.h>
#include <hip/hip_bf16.h>
#include <math.h>

namespace {
constexpr int M  = 48;    // fields
constexpr int D  = 128;   // embedding dim
constexpr int DH = 64;    // d's per block (d-half)
constexpr int H1 = 68;
constexpr int H2 = 32;
constexpr int H3 = 24;
constexpr int K1 = M  * M;   // 2304
constexpr int K2 = H1 * M;   // 3264
constexpr int K3 = H2 * M;   // 1536
constexpr int HOP1 = 96;     // H1 padded to 3 N-tiles of 32
constexpr int HOP2 = 32;
constexpr int HOP3 = 32;
// ws layout (ushort elements for weights, then float arrays)
constexpr int E1 = (K1 / 8) * HOP1 * 8;   // 221184
constexpr int E2 = (K2 / 8) * HOP2 * 8;   // 104448
constexpr int E3 = (K3 / 8) * HOP3 * 8;   //  49152
constexpr int EF = (M * D) * 64;          // 393216  fc1_w bf16
constexpr int EW = E1 + E2 + E3 + EF;     // 768000 ushorts
// float region offsets (in floats, from wsf base)
constexpr int OPOOL = 0;                  // ppool[1024][128]
constexpr int OH1P  = 1024 * 128;         // h1p[1024][64]
constexpr int X0S = 56;  // x0h f16 stride (112 B rows -> 16B-aligned half8 loads)
constexpr int BAS = 69;  // bufA f16 stride
constexpr int BBS = 33;  // bufB f16 stride
constexpr float BN_SCALE = 0.9995003746877732f;  // 1/sqrt(1+1e-3)
// prep thread-space
constexpr int P1 = (K1 / 8) * HOP1;  // 27648
constexpr int P2 = (K2 / 8) * HOP2;  // 13056
constexpr int P3 = (K3 / 8) * HOP3;  //  6144
constexpr int P4 = EF / 8;           // 49152
}

typedef __attribute__((ext_vector_type(8)))  _Float16 half8;
typedef __attribute__((ext_vector_type(16))) float f32x16;
typedef __attribute__((ext_vector_type(8)))  unsigned short us8;

static __device__ __forceinline__ unsigned short f2bs(float f) {  // bf16 RNE (fc1 path)
    __hip_bfloat16 h = __float2bfloat16(f);
    return __builtin_bit_cast(unsigned short, h);
}
static __device__ __forceinline__ unsigned short f2hs(float f) {  // f16 RNE
    _Float16 h = (_Float16)f;
    return __builtin_bit_cast(unsigned short, h);
}
static __device__ __forceinline__ float hs2f(unsigned short u) {  // f16 -> f32
    return (float)__builtin_bit_cast(_Float16, u);
}

// ---------------- prep: transpose+convert weights into d_ws ------------------
// n8-major: ws[n8*HOP*8 + o*8 + i] = W[n8*8+i][o] (o<HOP pad 0), f16 for MFMA.
// fc1_w stays bf16 (shift-based unpack in fc1 partial).
__global__ __launch_bounds__(256)
void prep_kernel(const float* __restrict__ w1, const float* __restrict__ w2,
                 const float* __restrict__ w3, const float* __restrict__ fc1w,
                 unsigned short* __restrict__ ws)
{
    const int tid = blockIdx.x * 256 + threadIdx.x;
    us8 v;
    if (tid < P1) {
        const int k8 = tid / HOP1, o = tid - k8 * HOP1;
        #pragma unroll
        for (int i = 0; i < 8; ++i)
            v[i] = (o < H1) ? f2hs(w1[(k8 * 8 + i) * H1 + o]) : (unsigned short)0;
        *(uint4*)(ws + (size_t)k8 * (HOP1 * 8) + o * 8) = __builtin_bit_cast(uint4, v);
    } else if (tid < P1 + P2) {
        const int x = tid - P1;
        const int k8 = x >> 5, o = x & 31;
        #pragma unroll
        for (int i = 0; i < 8; ++i)
            v[i] = f2hs(w2[(k8 * 8 + i) * H2 + o]);
        *(uint4*)(ws + E1 + (size_t)k8 * (HOP2 * 8) + o * 8) = __builtin_bit_cast(uint4, v);
    } else if (tid < P1 + P2 + P3) {
        const int x = tid - (P1 + P2);
        const int k8 = x >> 5, o = x & 31;
        #pragma unroll
        for (int i = 0; i < 8; ++i)
            v[i] = (o < H3) ? f2hs(w3[(k8 * 8 + i) * H3 + o]) : (unsigned short)0;
        *(uint4*)(ws + E1 + E2 + (size_t)k8 * (HOP3 * 8) + o * 8) = __builtin_bit_cast(uint4, v);
    } else if (tid < P1 + P2 + P3 + P4) {
        const int x = tid - (P1 + P2 + P3);
        const float4 a = ((const float4*)fc1w)[x * 2];
        const float4 b = ((const float4*)fc1w)[x * 2 + 1];
        v[0] = f2bs(a.x); v[1] = f2bs(a.y); v[2] = f2bs(a.z); v[3] = f2bs(a.w);
        v[4] = f2bs(b.x); v[5] = f2bs(b.y); v[6] = f2bs(b.z); v[7] = f2bs(b.w);
        *(uint4*)(ws + E1 + E2 + E3 + (size_t)x * 8) = __builtin_bit_cast(uint4, v);
    }
}

// ---------------- CIN layer via 32x32x16 f16 MFMA; block = (b, d-half) -------
// C[d][o] = sum_n A[d][n]*W[n][o], n = k*48+j, A[d][n] = xk[d][k]*x0[d][j].
// n = ks*16 + 8*h2 + i => k = ks/3 (1 xk splat / 3 ksteps), j = (2*(ks%3)+h2)*8+i
// -> 3 fixed half8 q8[] registers per layer. A-build: 4 v_pk_mul_f16 ONLY.
// 4 waves = (tile: 2 x 32 rows) x (khalf); khalf combine store->barrier->add.
// B-prefetch: NS-slot rotation (NS=3 for NT=3 layer-1, NS=6 for NT=1 layers —
// doubles in-flight work where per-phase MFMA is smallest). Tail prefetches run
// <=NS-1 ksteps past the layer region but stay inside d_ws (never consumed).
// NO device-scope fences (per-XCD L2 writeback — R10 regression).
template<int KTOT, int HO, int NT, int HOP, int NS, bool WRITEBUF>
__device__ __forceinline__ void cin_mfma(
    const unsigned short* __restrict__ x0h,
    const unsigned short* __restrict__ xksrc, int xkstride,
    const unsigned short* __restrict__ wt,
    unsigned short* __restrict__ outbuf, int outstride,
    float* __restrict__ pool, int poff, int t)
{
    const int lane  = t & 63;
    const int w     = t >> 6;
    const int tile  = w & 1;
    const int khalf = w >> 1;
    const int o0 = lane & 31, h2 = lane >> 5;
    const int dl = tile * 32 + o0;          // this lane's A-row (local d)
    constexpr int KS = KTOT / 16;
    constexpr int KH = KS / 2;
    static_assert(KH % 6 == 0, "K-half must be a multiple of 6 ksteps");
    static_assert(NS == 3 || NS == 6, "NS must divide the 6-kstep group");
    const int ks0 = khalf * KH;
    const int kb0 = ks0 / 3;

    // x0 j-operands: 3 fixed half8 registers for the whole layer (16B-aligned)
    half8 q8[3];
    #pragma unroll
    for (int p = 0; p < 3; ++p)
        q8[p] = *(const half8*)(x0h + dl * X0S + (2 * p + h2) * 8);

    f32x16 acc[NT];
    #pragma unroll
    for (int nt = 0; nt < NT; ++nt)
        #pragma unroll
        for (int r = 0; r < 16; ++r) acc[nt][r] = 0.f;

    const unsigned short* xkrow = xksrc + dl * xkstride;
    const unsigned short* wb = wt + (size_t)(h2 * HOP + o0) * 8;

    auto xsplat = [&](int k) -> half8 {
        const unsigned int xp = (unsigned int)xkrow[k] * 0x10001u;
        uint4 s; s.x = xp; s.y = xp; s.z = xp; s.w = xp;
        return __builtin_bit_cast(half8, s);
    };

    uint4 br[NS][NT];
    auto loadB = [&](int ks, uint4* b) {
        const unsigned short* p = wb + (size_t)ks * (2 * HOP * 8);
        #pragma unroll
        for (int nt = 0; nt < NT; ++nt)
            b[nt] = *(const uint4*)(p + nt * 256);
    };
    auto phase = [&](int p, half8 xs, const uint4* b) {
        const half8 av = xs * q8[p];          // 4 v_pk_mul_f16
        #pragma unroll
        for (int nt = 0; nt < NT; ++nt)
            acc[nt] = __builtin_amdgcn_mfma_f32_32x32x16_f16(
                av, __builtin_bit_cast(half8, b[nt]), acc[nt], 0, 0, 0);
    };

    #pragma unroll
    for (int s = 0; s < NS; ++s) loadB(ks0 + s, br[s]);
    half8 xs0 = xsplat(kb0);
    #pragma unroll 1
    for (int it = 0; it < KH / 6; ++it) {
        const int g  = ks0 + it * 6;
        const int kb = kb0 + it * 2;
        const half8 xs1 = xsplat(kb + 1);
        phase(0, xs0, br[0 % NS]);  loadB(g + NS + 0, br[0 % NS]);
        phase(1, xs0, br[1 % NS]);  loadB(g + NS + 1, br[1 % NS]);
        phase(2, xs0, br[2 % NS]);  loadB(g + NS + 2, br[2 % NS]);
        const half8 xsn = xsplat(kb + 2);   // in-row-pad at last iter (dead value)
        phase(0, xs1, br[3 % NS]);  loadB(g + NS + 3, br[3 % NS]);
        phase(1, xs1, br[4 % NS]);  loadB(g + NS + 4, br[4 % NS]);
        phase(2, xs1, br[5 % NS]);  loadB(g + NS + 5, br[5 % NS]);
        xs0 = xsn;
    }

    // epilogue: pool partials + khalf=0 stores (f16), barrier, khalf=1 adds
    const int dbase = tile * 32 + 4 * h2;
    #pragma unroll
    for (int nt = 0; nt < NT; ++nt) {
        const int o = nt * 32 + o0;
        if (o < HO) {
            float s = 0.f;
            #pragma unroll
            for (int r = 0; r < 16; ++r) s += acc[nt][r];
            if (WRITEBUF && khalf == 0) {
                #pragma unroll
                for (int r = 0; r < 16; ++r)
                    outbuf[(dbase + (r & 3) + 8 * (r >> 2)) * outstride + o] = f2hs(acc[nt][r]);
            }
            s += __shfl_xor(s, 32, 64);   // combine h2 halves (same o, disjoint rows)
            if (lane < 32) atomicAdd(&pool[poff + o], s);
        }
    }
    if (WRITEBUF) {
        __syncthreads();                  // khalf=0 partials visible
        if (khalf == 1) {
            #pragma unroll
            for (int nt = 0; nt < NT; ++nt) {
                const int o = nt * 32 + o0;
                if (o < HO) {
                    #pragma unroll
                    for (int r = 0; r < 16; ++r) {
                        const int idx = (dbase + (r & 3) + 8 * (r >> 2)) * outstride + o;
                        outbuf[idx] = f2hs(hs2f(outbuf[idx]) + acc[nt][r]);
                    }
                }
            }
        }
        __syncthreads();                  // combined buf visible to next layer
    }
}

__global__ __launch_bounds__(256, 4)
void dcin_kernel(const int*   __restrict__ x,
                 const float* __restrict__ emb,
                 const unsigned short* __restrict__ ws,   // f16/bf16 weights
                 float* __restrict__ wsf)                 // float partial region
{
    __shared__ __align__(16) unsigned short x0h [DH * X0S];   // 7168 B f16 embeds
    __shared__ __align__(16) unsigned short bufA[DH * BAS];   // 8832 B f16 L1 out
    __shared__ __align__(16) unsigned short bufB[DH * BBS];   // 4224 B f16 L2 out
    __shared__ float pool_s[H1 + H2 + H3];
    __shared__ int   sx[M];
    float* const red2 = (float*)bufB;    // 512 floats (2048B <= 4224B), after layer 3

    const unsigned short* wt1  = ws;
    const unsigned short* wt2  = ws + E1;
    const unsigned short* wt3  = ws + E1 + E2;
    const unsigned short* fc1b = ws + E1 + E2 + E3;

    const int b = blockIdx.x >> 1;
    const int h = blockIdx.x & 1;      // d-half
    const int t = threadIdx.x;

    if (t < M) sx[t] = x[b * M + t];
    if (t < H1 + H2 + H3) pool_s[t] = 0.f;
    __syncthreads();

    // gather x0h[dl][j] = f16(emb[sx[j]][h*64+dl]); j-fast writes
    for (int i = t; i < M * (DH / 4); i += 256) {
        const int c = i / 48;              // local float4 index 0..15
        const int j = i - c * 48;
        const float4 v = ((const float4*)(emb + (size_t)sx[j] * D))[h * 16 + c];
        x0h[(4 * c + 0) * X0S + j] = f2hs(v.x);
        x0h[(4 * c + 1) * X0S + j] = f2hs(v.y);
        x0h[(4 * c + 2) * X0S + j] = f2hs(v.z);
        x0h[(4 * c + 3) * X0S + j] = f2hs(v.w);
    }
    __syncthreads();

    // ---- CIN layers (32x32x16 f16 MFMA, f16 A-build) ----
    cin_mfma<K1, H1, 3, HOP1, 3, true >(x0h, x0h,  X0S, wt1, bufA, BAS, pool_s, 0, t);
    cin_mfma<K2, H2, 1, HOP2, 6, true >(x0h, bufA, BAS, wt2, bufB, BBS, pool_s, H1, t);
    cin_mfma<K3, H3, 1, HOP3, 6, false>(x0h, bufB, BBS, wt3, nullptr, 0, pool_s, H1 + H2, t);
    __syncthreads();   // pool complete, bufB (red2 alias) dead

    // ---- fc1 partial for this d-half (bf16 weights, f16 x0), no bias/act ----
    {
        const int u2 = (t & 31) * 2;
        const int part = t >> 5;          // 8 parts x 6 fields
        float a0 = 0.f, a1 = 0.f;
        for (int j = part * 6; j < part * 6 + 6; ++j) {
            const unsigned short* xr = x0h + j;
            #pragma unroll 4
            for (int d = 0; d < DH; ++d) {
                const float xv = hs2f(xr[d * X0S]);
                const unsigned int wp = *(const unsigned int*)(
                    fc1b + (size_t)(j * D + h * DH + d) * 64 + u2);
                a0 = fmaf(xv, __builtin_bit_cast(float, wp << 16), a0);
                a1 = fmaf(xv, __builtin_bit_cast(float, wp & 0xffff0000u), a1);
            }
        }
        red2[t * 2]     = a0;
        red2[t * 2 + 1] = a1;
    }
    __syncthreads();

    // ---- store partials to global ----
    const int slot = b * 2 + h;
    if (t < 64) {
        float v = 0.f;
        #pragma unroll
        for (int p = 0; p < 8; ++p)
            v += red2[(p * 32 + (t >> 1)) * 2 + (t & 1)];
        wsf[OH1P + slot * 64 + t] = v;
    }
    if (t >= 64 && t < 64 + H1 + H2 + H3)
        wsf[OPOOL + slot * 128 + (t - 64)] = pool_s[t - 64];
}

// ---------------- tail: combine halves + fc chain + output -------------------
__global__ __launch_bounds__(64)
void tail_kernel(const int*   __restrict__ x,
                 const float* __restrict__ lin_w, const float* __restrict__ lin_b,
                 const float* __restrict__ fc1_b,
                 const float* __restrict__ bn1_g, const float* __restrict__ bn1_b,
                 const float* __restrict__ fc2_w, const float* __restrict__ fc2_b,
                 const float* __restrict__ bn2_g, const float* __restrict__ bn2_b,
                 const float* __restrict__ fc3_w, const float* __restrict__ fc3_b,
                 const float* __restrict__ bn3_g, const float* __restrict__ bn3_b,
                 const float* __restrict__ out_w, const float* __restrict__ out_b,
                 const float* __restrict__ wsf,
                 float* __restrict__ out)
{
    __shared__ float h1s[64], h2s[48], h3s[24];
    __shared__ float pool_s[H1 + H2 + H3];
    const int b = blockIdx.x;
    const int t = threadIdx.x;
    const int s0 = b * 2, s1 = b * 2 + 1;

    {
        float v = wsf[OH1P + s0 * 64 + t] + wsf[OH1P + s1 * 64 + t] + fc1_b[t];
        v = fmaxf(v, 0.f);
        h1s[t] = bn1_g[t] * v * BN_SCALE + bn1_b[t];
    }
    for (int i = t; i < H1 + H2 + H3; i += 64)
        pool_s[i] = wsf[OPOOL + s0 * 128 + i] + wsf[OPOOL + s1 * 128 + i];
    __syncthreads();

    if (t < 48) {
        float a = fc2_b[t];
        #pragma unroll 4
        for (int u = 0; u < 64; ++u) a = fmaf(h1s[u], fc2_w[u * 48 + t], a);
        a = tanhf(a);
        h2s[t] = bn2_g[t] * a * BN_SCALE + bn2_b[t];
    }
    __syncthreads();

    if (t < 24) {
        float a = fc3_b[t];
        #pragma unroll 4
        for (int u = 0; u < 48; ++u) a = fmaf(h2s[u], fc3_w[u * 24 + t], a);
        a = tanhf(a);
        h3s[t] = bn3_g[t] * a * BN_SCALE + bn3_b[t];
    }
    __syncthreads();

    if (t == 0) {
        float s = lin_b[0];
        for (int j = 0; j < M; ++j) s += (float)x[b * M + j] * lin_w[j];
        const float slin = tanhf(s);
        float z = out_b[0];
        #pragma unroll 4
        for (int i = 0; i < H3; ++i) z = fmaf(h3s[i], out_w[i], z);
        z = fmaf(slin, out_w[H3], z);
        #pragma unroll 4
        for (int i = 0; i < H1 + H2 + H3; ++i)
            z = fmaf(pool_s[i], out_w[H3 + 1 + i], z);
        out[b] = 1.f / (1.f + expf(-z));
    }
}

extern "C" void kernel_launch(void* const* d_in, const int* in_sizes, int n_in,
                              void* d_out, int out_size, void* d_ws, size_t ws_size,
                              hipStream_t stream) {
    (void)in_sizes; (void)n_in; (void)ws_size; (void)out_size;
    const int*   x     = (const int*)  d_in[0];
    const float* emb   = (const float*)d_in[1];
    const float* w1    = (const float*)d_in[2];
    const float* w2    = (const float*)d_in[3];
    const float* w3    = (const float*)d_in[4];
    const float* lin_w = (const float*)d_in[5];
    const float* lin_b = (const float*)d_in[6];
    const float* fc1_w = (const float*)d_in[7];
    const float* fc1_b = (const float*)d_in[8];
    const float* bn1_g = (const float*)d_in[9];
    const float* bn1_b = (const float*)d_in[10];
    const float* fc2_w = (const float*)d_in[11];
    const float* fc2_b = (const float*)d_in[12];
    const float* bn2_g = (const float*)d_in[13];
    const float* bn2_b = (const float*)d_in[14];
    const float* fc3_w = (const float*)d_in[15];
    const float* fc3_b = (const float*)d_in[16];
    const float* bn3_g = (const float*)d_in[17];
    const float* bn3_b = (const float*)d_in[18];
    const float* out_w = (const float*)d_in[19];
    const float* out_b = (const float*)d_in[20];
    unsigned short* ws = (unsigned short*)d_ws;
    float* wsf = (float*)(ws + EW);

    const int prep_threads = P1 + P2 + P3 + P4;
    prep_kernel<<<(prep_threads + 255) / 256, 256, 0, stream>>>(w1, w2, w3, fc1_w, ws);

    dcin_kernel<<<1024, 256, 0, stream>>>(x, emb, ws, wsf);

    tail_kernel<<<512, 64, 0, stream>>>(
        x, lin_w, lin_b, fc1_b, bn1_g, bn1_b,
        fc2_w, fc2_b, bn2_g, bn2_b,
        fc3_w, fc3_b, bn3_g, bn3_b,
        out_w, out_b, wsf, (float*)d_out);
}

// Round 18
// 191.459 us; speedup vs baseline: 1.1759x; 1.0202x over previous
//
#include <hip/hip_runtime.h>
#include <hip/hip_bf16.h>
#include <math.h>

namespace {
constexpr int M  = 48;    // fields
constexpr int D  = 128;   // embedding dim
constexpr int H1 = 68;
constexpr int H2 = 32;
constexpr int H3 = 24;
constexpr int PO = H1 + H2 + H3;  // 124
constexpr int K1 = M  * M;   // 2304
constexpr int K2 = H1 * M;   // 3264
constexpr int K3 = H2 * M;   // 1536
constexpr int HOP1 = 96;     // H1 padded to 3 N-tiles of 32
constexpr int HOP2 = 32;
constexpr int HOP3 = 32;
// ws layout (ushort elements)
constexpr int E1 = (K1 / 8) * HOP1 * 8;   // 221184
constexpr int E2 = (K2 / 8) * HOP2 * 8;   // 104448
constexpr int E3 = (K3 / 8) * HOP3 * 8;   //  49152
constexpr int EF = (M * D) * 64;          // 393216  fc1_w bf16
constexpr int X0S = 56;  // x0h f16 stride (112 B rows -> 16B-aligned half8 loads)
constexpr int BAS = 69;  // bufA f16 stride
constexpr int BBS = 33;  // bufB f16 stride
constexpr float BN_SCALE = 0.9995003746877732f;  // 1/sqrt(1+1e-3)
// prep thread-space
constexpr int P1 = (K1 / 8) * HOP1;  // 27648
constexpr int P2 = (K2 / 8) * HOP2;  // 13056
constexpr int P3 = (K3 / 8) * HOP3;  //  6144
constexpr int P4 = EF / 8;           // 49152
}

typedef __attribute__((ext_vector_type(8)))  _Float16 half8;
typedef __attribute__((ext_vector_type(16))) float f32x16;
typedef __attribute__((ext_vector_type(8)))  unsigned short us8;

static __device__ __forceinline__ unsigned short f2bs(float f) {  // bf16 RNE (fc1 path)
    __hip_bfloat16 h = __float2bfloat16(f);
    return __builtin_bit_cast(unsigned short, h);
}
static __device__ __forceinline__ unsigned short f2hs(float f) {  // f16 RNE
    _Float16 h = (_Float16)f;
    return __builtin_bit_cast(unsigned short, h);
}
static __device__ __forceinline__ float hs2f(unsigned short u) {  // f16 -> f32
    return (float)__builtin_bit_cast(_Float16, u);
}

// ---------------- prep: transpose+convert weights into d_ws ------------------
// n8-major: ws[n8*HOP*8 + o*8 + i] = W[n8*8+i][o] (o<HOP pad 0), f16 for MFMA.
// fc1_w stays bf16 (shift-based unpack in fc1 partial).
__global__ __launch_bounds__(256)
void prep_kernel(const float* __restrict__ w1, const float* __restrict__ w2,
                 const float* __restrict__ w3, const float* __restrict__ fc1w,
                 unsigned short* __restrict__ ws)
{
    const int tid = blockIdx.x * 256 + threadIdx.x;
    us8 v;
    if (tid < P1) {
        const int k8 = tid / HOP1, o = tid - k8 * HOP1;
        #pragma unroll
        for (int i = 0; i < 8; ++i)
            v[i] = (o < H1) ? f2hs(w1[(k8 * 8 + i) * H1 + o]) : (unsigned short)0;
        *(uint4*)(ws + (size_t)k8 * (HOP1 * 8) + o * 8) = __builtin_bit_cast(uint4, v);
    } else if (tid < P1 + P2) {
        const int x = tid - P1;
        const int k8 = x >> 5, o = x & 31;
        #pragma unroll
        for (int i = 0; i < 8; ++i)
            v[i] = f2hs(w2[(k8 * 8 + i) * H2 + o]);
        *(uint4*)(ws + E1 + (size_t)k8 * (HOP2 * 8) + o * 8) = __builtin_bit_cast(uint4, v);
    } else if (tid < P1 + P2 + P3) {
        const int x = tid - (P1 + P2);
        const int k8 = x >> 5, o = x & 31;
        #pragma unroll
        for (int i = 0; i < 8; ++i)
            v[i] = (o < H3) ? f2hs(w3[(k8 * 8 + i) * H3 + o]) : (unsigned short)0;
        *(uint4*)(ws + E1 + E2 + (size_t)k8 * (HOP3 * 8) + o * 8) = __builtin_bit_cast(uint4, v);
    } else if (tid < P1 + P2 + P3 + P4) {
        const int x = tid - (P1 + P2 + P3);
        const float4 a = ((const float4*)fc1w)[x * 2];
        const float4 b = ((const float4*)fc1w)[x * 2 + 1];
        v[0] = f2bs(a.x); v[1] = f2bs(a.y); v[2] = f2bs(a.z); v[3] = f2bs(a.w);
        v[4] = f2bs(b.x); v[5] = f2bs(b.y); v[6] = f2bs(b.z); v[7] = f2bs(b.w);
        *(uint4*)(ws + E1 + E2 + E3 + (size_t)x * 8) = __builtin_bit_cast(uint4, v);
    }
}

// ---------------- CIN layer via 32x32x16 f16 MFMA; block = batch row ----------
// 8 waves = (tile: 4 x 32 rows over 128 d) x (khalf: 2). A-build: 4 v_pk_mul_f16.
// NS-slot B rotation (NS=3 for NT=3, NS=6 for NT=1). khalf combine
// store->barrier->add. NO device-scope fences (R10 regression).
template<int KTOT, int HO, int NT, int HOP, int NS>
__device__ __forceinline__ void cin_mfma(
    const unsigned short* __restrict__ x0h,
    const unsigned short* __restrict__ xksrc, int xkstride,
    const unsigned short* __restrict__ wt,
    unsigned short* __restrict__ outbuf, int outstride,
    float* __restrict__ pool, int poff, int t)
{
    const int lane  = t & 63;
    const int w     = t >> 6;
    const int tile  = w & 3;
    const int khalf = w >> 2;
    const int o0 = lane & 31, h2 = lane >> 5;
    const int dl = tile * 32 + o0;          // this lane's A-row (local d, 0..127)
    constexpr int KS = KTOT / 16;
    constexpr int KH = KS / 2;
    static_assert(KH % 6 == 0, "K-half must be a multiple of 6 ksteps");
    static_assert(NS == 3 || NS == 6, "NS must divide the 6-kstep group");
    const int ks0 = khalf * KH;
    const int kb0 = ks0 / 3;

    half8 q8[3];
    #pragma unroll
    for (int p = 0; p < 3; ++p)
        q8[p] = *(const half8*)(x0h + dl * X0S + (2 * p + h2) * 8);

    f32x16 acc[NT];
    #pragma unroll
    for (int nt = 0; nt < NT; ++nt)
        #pragma unroll
        for (int r = 0; r < 16; ++r) acc[nt][r] = 0.f;

    const unsigned short* xkrow = xksrc + dl * xkstride;
    const unsigned short* wb = wt + (size_t)(h2 * HOP + o0) * 8;

    auto xsplat = [&](int k) -> half8 {
        const unsigned int xp = (unsigned int)xkrow[k] * 0x10001u;
        uint4 s; s.x = xp; s.y = xp; s.z = xp; s.w = xp;
        return __builtin_bit_cast(half8, s);
    };

    uint4 br[NS][NT];
    auto loadB = [&](int ks, uint4* b) {
        const unsigned short* p = wb + (size_t)ks * (2 * HOP * 8);
        #pragma unroll
        for (int nt = 0; nt < NT; ++nt)
            b[nt] = *(const uint4*)(p + nt * 256);
    };
    auto phase = [&](int p, half8 xs, const uint4* b) {
        const half8 av = xs * q8[p];
        #pragma unroll
        for (int nt = 0; nt < NT; ++nt)
            acc[nt] = __builtin_amdgcn_mfma_f32_32x32x16_f16(
                av, __builtin_bit_cast(half8, b[nt]), acc[nt], 0, 0, 0);
    };

    #pragma unroll
    for (int s = 0; s < NS; ++s) loadB(ks0 + s, br[s]);
    half8 xs0 = xsplat(kb0);
    #pragma unroll 1
    for (int it = 0; it < KH / 6; ++it) {
        const int g  = ks0 + it * 6;
        const int kb = kb0 + it * 2;
        const half8 xs1 = xsplat(kb + 1);
        phase(0, xs0, br[0 % NS]);  loadB(g + NS + 0, br[0 % NS]);
        phase(1, xs0, br[1 % NS]);  loadB(g + NS + 1, br[1 % NS]);
        phase(2, xs0, br[2 % NS]);  loadB(g + NS + 2, br[2 % NS]);
        const half8 xsn = xsplat(kb + 2);   // in-row-pad at last iter (dead value)
        phase(0, xs1, br[3 % NS]);  loadB(g + NS + 3, br[3 % NS]);
        phase(1, xs1, br[4 % NS]);  loadB(g + NS + 4, br[4 % NS]);
        phase(2, xs1, br[5 % NS]);  loadB(g + NS + 5, br[5 % NS]);
        xs0 = xsn;
    }

    // epilogue: pool partials + khalf=0 stores (f16), barrier, khalf=1 adds
    const int dbase = tile * 32 + 4 * h2;
    #pragma unroll
    for (int nt = 0; nt < NT; ++nt) {
        const int o = nt * 32 + o0;
        if (o < HO) {
            float s = 0.f;
            #pragma unroll
            for (int r = 0; r < 16; ++r) s += acc[nt][r];
            if (khalf == 0) {
                #pragma unroll
                for (int r = 0; r < 16; ++r)
                    outbuf[(dbase + (r & 3) + 8 * (r >> 2)) * outstride + o] = f2hs(acc[nt][r]);
            }
            s += __shfl_xor(s, 32, 64);
            if (lane < 32) atomicAdd(&pool[poff + o], s);
        }
    }
    __syncthreads();                  // khalf=0 partials visible
    if (khalf == 1) {
        #pragma unroll
        for (int nt = 0; nt < NT; ++nt) {
            const int o = nt * 32 + o0;
            if (o < HO) {
                #pragma unroll
                for (int r = 0; r < 16; ++r) {
                    const int idx = (dbase + (r & 3) + 8 * (r >> 2)) * outstride + o;
                    outbuf[idx] = f2hs(hs2f(outbuf[idx]) + acc[nt][r]);
                }
            }
        }
    }
    __syncthreads();                  // combined buf visible to next consumer
}

__global__ __launch_bounds__(512, 4)
void dcin_kernel(const int*   __restrict__ x,
                 const float* __restrict__ emb,
                 const unsigned short* __restrict__ ws,
                 const float* __restrict__ lin_w, const float* __restrict__ lin_b,
                 const float* __restrict__ fc1_b,
                 const float* __restrict__ bn1_g, const float* __restrict__ bn1_b,
                 const float* __restrict__ fc2_w, const float* __restrict__ fc2_b,
                 const float* __restrict__ bn2_g, const float* __restrict__ bn2_b,
                 const float* __restrict__ fc3_w, const float* __restrict__ fc3_b,
                 const float* __restrict__ bn3_g, const float* __restrict__ bn3_b,
                 const float* __restrict__ out_w, const float* __restrict__ out_b,
                 float* __restrict__ out)
{
    __shared__ __align__(16) unsigned short x0h [D * X0S + 16];  // 14368 B (+pad for Gram j-overrun)
    __shared__ __align__(16) unsigned short bufA[D * BAS];       // 17664 B (red2/Gs alias after L2)
    __shared__ __align__(16) unsigned short bufB[D * BBS];       //  8448 B
    __shared__ float pool_s[PO];
    __shared__ int   sx[M];
    __shared__ float h1s[64], h2s[48], h3s[24];
    float* const red2 = (float*)bufA;                 // 768 floats (3072 B)
    float* const Gs   = (float*)(bufA + 2048);        // 1536 floats @ byte 4096..10240

    const unsigned short* wt1  = ws;
    const unsigned short* wt2  = ws + E1;
    const unsigned short* wt3  = ws + E1 + E2;
    const unsigned short* fc1b = ws + E1 + E2 + E3;

    const int b = blockIdx.x;
    const int t = threadIdx.x;

    if (t < M) sx[t] = x[b * M + t];
    if (t < PO) pool_s[t] = 0.f;
    __syncthreads();

    // gather x0h[dl][j] = f16(emb[sx[j]][dl]), all 128 d; j-fast writes
    for (int i = t; i < M * (D / 4); i += 512) {
        const int c = i / 48;              // float4 index 0..31
        const int j = i - c * 48;
        const float4 v = ((const float4*)(emb + (size_t)sx[j] * D))[c];
        x0h[(4 * c + 0) * X0S + j] = f2hs(v.x);
        x0h[(4 * c + 1) * X0S + j] = f2hs(v.y);
        x0h[(4 * c + 2) * X0S + j] = f2hs(v.z);
        x0h[(4 * c + 3) * X0S + j] = f2hs(v.w);
    }
    __syncthreads();

    // ---- CIN layers 1,2 (32x32x16 f16 MFMA) ----
    cin_mfma<K1, H1, 3, HOP1, 3>(x0h, x0h,  X0S, wt1, bufA, BAS, pool_s, 0, t);
    cin_mfma<K2, H2, 1, HOP2, 6>(x0h, bufA, BAS, wt2, bufB, BBS, pool_s, H1, t);
    // bufB = C2 complete; bufA dead (red2/Gs alias live from here).

    // ---- layer 3 via Gram: pool3[o] = sum_n G[n] W3[n][o],
    //      G[k][j] = sum_d bufB[d][k] * x0h[d][j]  (exact pooling identity).
    //      Waves 0,1: Gram j-tiles. Waves 2..7: fc1 partials (concurrent). ----
    const int w = t >> 6;
    if (w < 2) {
        const int lane = t & 63, m = lane & 31, h2g = lane >> 5;
        f32x16 g;
        #pragma unroll
        for (int r = 0; r < 16; ++r) g[r] = 0.f;
        #pragma unroll 1
        for (int s = 0; s < 8; ++s) {      // K = 128 d, 16 per MFMA
            us8 a8, b8;
            #pragma unroll
            for (int i = 0; i < 8; ++i) {
                const int d = s * 16 + h2g * 8 + i;
                a8[i] = bufB[d * BBS + m];               // A[k=m][d]
                b8[i] = x0h[d * X0S + w * 32 + m];       // B[d][j=w*32+m]
            }
            g = __builtin_amdgcn_mfma_f32_32x32x16_f16(
                __builtin_bit_cast(half8, a8), __builtin_bit_cast(half8, b8), g, 0, 0, 0);
        }
        #pragma unroll
        for (int r = 0; r < 16; ++r) {
            const int k = (r & 3) + 8 * (r >> 2) + 4 * h2g;
            const int j = w * 32 + m;
            if (j < 48) Gs[k * 48 + j] = g[r];
        }
    } else {
        // fc1 partial (bf16 weights, f16 x0): waves 2..7, 12 parts x 4 fields
        const int tl = t - 128;
        const int u2 = (tl & 31) * 2;
        const int part = tl >> 5;          // 0..11
        float a0 = 0.f, a1 = 0.f;
        for (int j = part * 4; j < part * 4 + 4; ++j) {
            const unsigned short* xr = x0h + j;
            #pragma unroll 4
            for (int d = 0; d < D; ++d) {
                const float xv = hs2f(xr[d * X0S]);
                const unsigned int wp = *(const unsigned int*)(
                    fc1b + ((size_t)j * D + d) * 64 + u2);
                a0 = fmaf(xv, __builtin_bit_cast(float, wp << 16), a0);
                a1 = fmaf(xv, __builtin_bit_cast(float, wp & 0xffff0000u), a1);
            }
        }
        red2[tl * 2]     = a0;
        red2[tl * 2 + 1] = a1;
    }
    __syncthreads();

    // ---- pool3 GEMV (384 threads) + h1 combine (64 threads), concurrent ----
    if (t < 384) {
        const int o = t % 24, seg = t / 24;   // 16 segs x 96 n's
        float a = 0.f;
        for (int n = seg * 96; n < seg * 96 + 96; ++n)
            a = fmaf(Gs[n], hs2f(wt3[(n >> 3) * (HOP3 * 8) + o * 8 + (n & 7)]), a);
        atomicAdd(&pool_s[H1 + H2 + o], a);
    } else if (t < 448) {
        const int uo = t - 384;
        float v = fc1_b[uo];
        #pragma unroll
        for (int p = 0; p < 12; ++p)
            v += red2[(p * 32 + (uo >> 1)) * 2 + (uo & 1)];
        v = fmaxf(v, 0.f);
        h1s[uo] = bn1_g[uo] * v * BN_SCALE + bn1_b[uo];
    }
    __syncthreads();

    if (t < 48) {
        float a = fc2_b[t];
        #pragma unroll 4
        for (int u = 0; u < 64; ++u) a = fmaf(h1s[u], fc2_w[u * 48 + t], a);
        a = tanhf(a);
        h2s[t] = bn2_g[t] * a * BN_SCALE + bn2_b[t];
    }
    __syncthreads();

    if (t < 24) {
        float a = fc3_b[t];
        #pragma unroll 4
        for (int u = 0; u < 48; ++u) a = fmaf(h2s[u], fc3_w[u * 24 + t], a);
        a = tanhf(a);
        h3s[t] = bn3_g[t] * a * BN_SCALE + bn3_b[t];
    }
    __syncthreads();

    if (t == 0) {
        float s = lin_b[0];
        for (int j = 0; j < M; ++j) s += (float)sx[j] * lin_w[j];
        const float slin = tanhf(s);
        float z = out_b[0];
        #pragma unroll 4
        for (int i = 0; i < H3; ++i) z = fmaf(h3s[i], out_w[i], z);
        z = fmaf(slin, out_w[H3], z);
        #pragma unroll 4
        for (int i = 0; i < PO; ++i)
            z = fmaf(pool_s[i], out_w[H3 + 1 + i], z);
        out[b] = 1.f / (1.f + expf(-z));
    }
}

extern "C" void kernel_launch(void* const* d_in, const int* in_sizes, int n_in,
                              void* d_out, int out_size, void* d_ws, size_t ws_size,
                              hipStream_t stream) {
    (void)in_sizes; (void)n_in; (void)ws_size; (void)out_size;
    const int*   x     = (const int*)  d_in[0];
    const float* emb   = (const float*)d_in[1];
    const float* w1    = (const float*)d_in[2];
    const float* w2    = (const float*)d_in[3];
    const float* w3    = (const float*)d_in[4];
    const float* lin_w = (const float*)d_in[5];
    const float* lin_b = (const float*)d_in[6];
    const float* fc1_w = (const float*)d_in[7];
    const float* fc1_b = (const float*)d_in[8];
    const float* bn1_g = (const float*)d_in[9];
    const float* bn1_b = (const float*)d_in[10];
    const float* fc2_w = (const float*)d_in[11];
    const float* fc2_b = (const float*)d_in[12];
    const float* bn2_g = (const float*)d_in[13];
    const float* bn2_b = (const float*)d_in[14];
    const float* fc3_w = (const float*)d_in[15];
    const float* fc3_b = (const float*)d_in[16];
    const float* bn3_g = (const float*)d_in[17];
    const float* bn3_b = (const float*)d_in[18];
    const float* out_w = (const float*)d_in[19];
    const float* out_b = (const float*)d_in[20];
    unsigned short* ws = (unsigned short*)d_ws;

    const int prep_threads = P1 + P2 + P3 + P4;
    prep_kernel<<<(prep_threads + 255) / 256, 256, 0, stream>>>(w1, w2, w3, fc1_w, ws);

    dcin_kernel<<<512, 512, 0, stream>>>(
        x, emb, ws,
        lin_w, lin_b, fc1_b, bn1_g, bn1_b,
        fc2_w, fc2_b, bn2_g, bn2_b,
        fc3_w, fc3_b, bn3_g, bn3_b,
        out_w, out_b, (float*)d_out);
}

// Round 19
// 189.988 us; speedup vs baseline: 1.1850x; 1.0077x over previous
//
#include <hip/hip_runtime.h>
#include <hip/hip_bf16.h>
#include <math.h>

namespace {
constexpr int M  = 48;    // fields
constexpr int D  = 128;   // embedding dim
constexpr int H1 = 68;
constexpr int H2 = 32;
constexpr int H3 = 24;
constexpr int PO = H1 + H2 + H3;  // 124
constexpr int K1 = M  * M;   // 2304
constexpr int K2 = H1 * M;   // 3264
constexpr int HOP1 = 96;     // H1 padded to 3 N-tiles of 32
constexpr int HOP2 = 32;
constexpr int HOP3 = 32;
// ws layout (ushort elements)
constexpr int E1 = (K1 / 8) * HOP1 * 8;   // 221184
constexpr int E2 = (K2 / 8) * HOP2 * 8;   // 104448
constexpr int E3 = ((H2 * M) / 8) * HOP3 * 8; // 49152 (n8-major w3, kept for Gram-free paths)
constexpr int EF = (M * D) * 64;          // 393216  fc1_w bf16
constexpr int EW = E1 + E2 + E3 + EF;     // 768000
constexpr int ET = 24 * 1536;             // 36864  wt3v[o][n] f16 (GEMV layout)
constexpr int X0S = 56;  // x0h f16 stride (112 B rows -> 16B-aligned half8 loads)
constexpr int BAS = 69;  // bufA f16 stride
constexpr int BBS = 33;  // bufB f16 stride
constexpr float BN_SCALE = 0.9995003746877732f;  // 1/sqrt(1+1e-3)
// prep thread-space
constexpr int P1 = (K1 / 8) * HOP1;       // 27648
constexpr int P2 = ((H1 * M) / 8) * HOP2; // 13056
constexpr int P3 = ((H2 * M) / 8) * HOP3; //  6144
constexpr int P4 = EF / 8;                // 49152
constexpr int P5 = ET / 8;                //  4608
}

typedef __attribute__((ext_vector_type(8)))  _Float16 half8;
typedef __attribute__((ext_vector_type(2)))  __fp16   fp16x2;
typedef __attribute__((ext_vector_type(16))) float f32x16;
typedef __attribute__((ext_vector_type(8)))  unsigned short us8;

static __device__ __forceinline__ unsigned short f2bs(float f) {  // bf16 RNE (fc1 path)
    __hip_bfloat16 h = __float2bfloat16(f);
    return __builtin_bit_cast(unsigned short, h);
}
static __device__ __forceinline__ unsigned short f2hs(float f) {  // f16 RNE
    _Float16 h = (_Float16)f;
    return __builtin_bit_cast(unsigned short, h);
}
static __device__ __forceinline__ float hs2f(unsigned short u) {  // f16 -> f32
    return (float)__builtin_bit_cast(_Float16, u);
}
static __device__ __forceinline__ unsigned int cvt2(float a, float b) {
    fp16x2 h = __builtin_amdgcn_cvt_pkrtz(a, b);
    return __builtin_bit_cast(unsigned int, h);
}

// ---------------- prep: transpose+convert weights into d_ws ------------------
// n8-major MFMA layouts for w1/w2/w3, bf16 copy of fc1_w, plus wt3v[o][n] f16
// (o-major, n-contiguous) for the pool3 GEMV.
__global__ __launch_bounds__(256)
void prep_kernel(const float* __restrict__ w1, const float* __restrict__ w2,
                 const float* __restrict__ w3, const float* __restrict__ fc1w,
                 unsigned short* __restrict__ ws)
{
    const int tid = blockIdx.x * 256 + threadIdx.x;
    us8 v;
    if (tid < P1) {
        const int k8 = tid / HOP1, o = tid - k8 * HOP1;
        #pragma unroll
        for (int i = 0; i < 8; ++i)
            v[i] = (o < H1) ? f2hs(w1[(k8 * 8 + i) * H1 + o]) : (unsigned short)0;
        *(uint4*)(ws + (size_t)k8 * (HOP1 * 8) + o * 8) = __builtin_bit_cast(uint4, v);
    } else if (tid < P1 + P2) {
        const int x = tid - P1;
        const int k8 = x >> 5, o = x & 31;
        #pragma unroll
        for (int i = 0; i < 8; ++i)
            v[i] = f2hs(w2[(k8 * 8 + i) * H2 + o]);
        *(uint4*)(ws + E1 + (size_t)k8 * (HOP2 * 8) + o * 8) = __builtin_bit_cast(uint4, v);
    } else if (tid < P1 + P2 + P3) {
        const int x = tid - (P1 + P2);
        const int k8 = x >> 5, o = x & 31;
        #pragma unroll
        for (int i = 0; i < 8; ++i)
            v[i] = (o < H3) ? f2hs(w3[(k8 * 8 + i) * H3 + o]) : (unsigned short)0;
        *(uint4*)(ws + E1 + E2 + (size_t)k8 * (HOP3 * 8) + o * 8) = __builtin_bit_cast(uint4, v);
    } else if (tid < P1 + P2 + P3 + P4) {
        const int x = tid - (P1 + P2 + P3);
        const float4 a = ((const float4*)fc1w)[x * 2];
        const float4 b = ((const float4*)fc1w)[x * 2 + 1];
        v[0] = f2bs(a.x); v[1] = f2bs(a.y); v[2] = f2bs(a.z); v[3] = f2bs(a.w);
        v[4] = f2bs(b.x); v[5] = f2bs(b.y); v[6] = f2bs(b.z); v[7] = f2bs(b.w);
        *(uint4*)(ws + E1 + E2 + E3 + (size_t)x * 8) = __builtin_bit_cast(uint4, v);
    } else if (tid < P1 + P2 + P3 + P4 + P5) {
        const int x = tid - (P1 + P2 + P3 + P4);
        const int o = x / 192, n0 = (x - o * 192) * 8;
        #pragma unroll
        for (int i = 0; i < 8; ++i)
            v[i] = f2hs(w3[(n0 + i) * H3 + o]);
        *(uint4*)(ws + EW + (size_t)o * 1536 + n0) = __builtin_bit_cast(uint4, v);
    }
}

// ---------------- CIN layer via 32x32x16 f16 MFMA; block = batch row ----------
// 8 waves = (tile: 4 x 32 rows over 128 d) x (khalf: 2). A-build: 4 v_pk_mul_f16.
// NS-slot B rotation. DUALOUT: khalf waves store DISJOINT buffers (ob0/ob1) ->
// single barrier, no RMW; consumer sums on read. XKDUAL: xk = f16(a0)+f16(a1).
// NO device-scope fences (R10 regression).
template<int KTOT, int HO, int NT, int HOP, int NS, bool DUALOUT, bool XKDUAL>
__device__ __forceinline__ void cin_mfma(
    const unsigned short* __restrict__ x0h,
    const unsigned short* __restrict__ xk0, const unsigned short* __restrict__ xk1,
    int xkstride,
    const unsigned short* __restrict__ wt,
    unsigned short* __restrict__ ob0, unsigned short* __restrict__ ob1,
    int outstride,
    float* __restrict__ pool, int poff, int t)
{
    const int lane  = t & 63;
    const int w     = t >> 6;
    const int tile  = w & 3;
    const int khalf = w >> 2;
    const int o0 = lane & 31, h2 = lane >> 5;
    const int dl = tile * 32 + o0;          // this lane's A-row (local d, 0..127)
    constexpr int KS = KTOT / 16;
    constexpr int KH = KS / 2;
    static_assert(KH % 6 == 0, "K-half must be a multiple of 6 ksteps");
    static_assert(NS == 3 || NS == 6, "NS must divide the 6-kstep group");
    const int ks0 = khalf * KH;
    const int kb0 = ks0 / 3;

    half8 q8[3];
    #pragma unroll
    for (int p = 0; p < 3; ++p)
        q8[p] = *(const half8*)(x0h + dl * X0S + (2 * p + h2) * 8);

    f32x16 acc[NT];
    #pragma unroll
    for (int nt = 0; nt < NT; ++nt)
        #pragma unroll
        for (int r = 0; r < 16; ++r) acc[nt][r] = 0.f;

    const unsigned short* xr0 = xk0 + dl * xkstride;
    const unsigned short* xr1 = XKDUAL ? (xk1 + dl * xkstride) : nullptr;
    const unsigned short* wb = wt + (size_t)(h2 * HOP + o0) * 8;

    auto xsplat = [&](int k) -> half8 {
        unsigned int xp;
        if (XKDUAL) {
            const float xv = hs2f(xr0[k]) + hs2f(xr1[k]);
            xp = cvt2(xv, xv);
        } else {
            xp = (unsigned int)xr0[k] * 0x10001u;
        }
        uint4 s; s.x = xp; s.y = xp; s.z = xp; s.w = xp;
        return __builtin_bit_cast(half8, s);
    };

    uint4 br[NS][NT];
    auto loadB = [&](int ks, uint4* b) {
        const unsigned short* p = wb + (size_t)ks * (2 * HOP * 8);
        #pragma unroll
        for (int nt = 0; nt < NT; ++nt)
            b[nt] = *(const uint4*)(p + nt * 256);
    };
    auto phase = [&](int p, half8 xs, const uint4* b) {
        const half8 av = xs * q8[p];
        #pragma unroll
        for (int nt = 0; nt < NT; ++nt)
            acc[nt] = __builtin_amdgcn_mfma_f32_32x32x16_f16(
                av, __builtin_bit_cast(half8, b[nt]), acc[nt], 0, 0, 0);
    };

    #pragma unroll
    for (int s = 0; s < NS; ++s) loadB(ks0 + s, br[s]);
    half8 xs0 = xsplat(kb0);
    #pragma unroll 1
    for (int it = 0; it < KH / 6; ++it) {
        const int g  = ks0 + it * 6;
        const int kb = kb0 + it * 2;
        const half8 xs1 = xsplat(kb + 1);
        phase(0, xs0, br[0 % NS]);  loadB(g + NS + 0, br[0 % NS]);
        phase(1, xs0, br[1 % NS]);  loadB(g + NS + 1, br[1 % NS]);
        phase(2, xs0, br[2 % NS]);  loadB(g + NS + 2, br[2 % NS]);
        const half8 xsn = xsplat(kb + 2);   // in-row-pad at last iter (dead value)
        phase(0, xs1, br[3 % NS]);  loadB(g + NS + 3, br[3 % NS]);
        phase(1, xs1, br[4 % NS]);  loadB(g + NS + 4, br[4 % NS]);
        phase(2, xs1, br[5 % NS]);  loadB(g + NS + 5, br[5 % NS]);
        xs0 = xsn;
    }

    // epilogue
    const int dbase = tile * 32 + 4 * h2;
    if (DUALOUT) {
        unsigned short* ob = khalf ? ob1 : ob0;
        #pragma unroll
        for (int nt = 0; nt < NT; ++nt) {
            const int o = nt * 32 + o0;
            if (o < HO) {
                float s = 0.f;
                #pragma unroll
                for (int r = 0; r < 16; ++r) s += acc[nt][r];
                #pragma unroll
                for (int r = 0; r < 16; ++r)
                    ob[(dbase + (r & 3) + 8 * (r >> 2)) * outstride + o] = f2hs(acc[nt][r]);
                s += __shfl_xor(s, 32, 64);
                if (lane < 32) atomicAdd(&pool[poff + o], s);
            }
        }
        __syncthreads();              // both partial buffers visible
    } else {
        #pragma unroll
        for (int nt = 0; nt < NT; ++nt) {
            const int o = nt * 32 + o0;
            if (o < HO) {
                float s = 0.f;
                #pragma unroll
                for (int r = 0; r < 16; ++r) s += acc[nt][r];
                if (khalf == 0) {
                    #pragma unroll
                    for (int r = 0; r < 16; ++r)
                        ob0[(dbase + (r & 3) + 8 * (r >> 2)) * outstride + o] = f2hs(acc[nt][r]);
                }
                s += __shfl_xor(s, 32, 64);
                if (lane < 32) atomicAdd(&pool[poff + o], s);
            }
        }
        __syncthreads();
        if (khalf == 1) {
            #pragma unroll
            for (int nt = 0; nt < NT; ++nt) {
                const int o = nt * 32 + o0;
                if (o < HO) {
                    #pragma unroll
                    for (int r = 0; r < 16; ++r) {
                        const int idx = (dbase + (r & 3) + 8 * (r >> 2)) * outstride + o;
                        ob0[idx] = f2hs(hs2f(ob0[idx]) + acc[nt][r]);
                    }
                }
            }
        }
        __syncthreads();
    }
}

__global__ __launch_bounds__(512, 4)
void dcin_kernel(const int*   __restrict__ x,
                 const float* __restrict__ emb,
                 const unsigned short* __restrict__ ws,
                 const float* __restrict__ lin_w, const float* __restrict__ lin_b,
                 const float* __restrict__ fc1_b,
                 const float* __restrict__ bn1_g, const float* __restrict__ bn1_b,
                 const float* __restrict__ fc2_w, const float* __restrict__ fc2_b,
                 const float* __restrict__ bn2_g, const float* __restrict__ bn2_b,
                 const float* __restrict__ fc3_w, const float* __restrict__ fc3_b,
                 const float* __restrict__ bn3_g, const float* __restrict__ bn3_b,
                 const float* __restrict__ out_w, const float* __restrict__ out_b,
                 float* __restrict__ out)
{
    __shared__ __align__(16) unsigned short x0h  [D * X0S + 16]; // 14368 B
    __shared__ __align__(16) unsigned short bufA0[D * BAS];      // 17664 B (khalf0 partial)
    __shared__ __align__(16) unsigned short bufA1[D * BAS];      // 17664 B (khalf1 partial)
    __shared__ __align__(16) unsigned short bufB [D * BBS];      //  8448 B
    __shared__ float pool_s[PO];
    __shared__ int   sx[M];
    __shared__ float h1s[64], h2s[48], h3s[24];
    float* const red2 = (float*)bufA0;                // 768 floats (bytes 0..3072)
    float* const Gs   = (float*)(bufA0 + 2048);       // 1536 floats (bytes 4096..10240)

    const unsigned short* wt1   = ws;
    const unsigned short* wt2   = ws + E1;
    const unsigned short* fc1b  = ws + E1 + E2 + E3;
    const unsigned short* wt3v  = ws + EW;            // [24][1536] f16

    const int b = blockIdx.x;
    const int t = threadIdx.x;

    if (t < M) sx[t] = x[b * M + t];
    if (t < PO) pool_s[t] = 0.f;
    __syncthreads();

    // gather x0h[dl][j] = f16(emb[sx[j]][dl]), all 128 d; j-fast writes
    for (int i = t; i < M * (D / 4); i += 512) {
        const int c = i / 48;              // float4 index 0..31
        const int j = i - c * 48;
        const float4 v = ((const float4*)(emb + (size_t)sx[j] * D))[c];
        x0h[(4 * c + 0) * X0S + j] = f2hs(v.x);
        x0h[(4 * c + 1) * X0S + j] = f2hs(v.y);
        x0h[(4 * c + 2) * X0S + j] = f2hs(v.z);
        x0h[(4 * c + 3) * X0S + j] = f2hs(v.w);
    }
    __syncthreads();

    // ---- CIN layer 1: dual-output (one barrier, no RMW) ----
    cin_mfma<K1, H1, 3, HOP1, 3, true, false>(
        x0h, x0h, nullptr, X0S, wt1, bufA0, bufA1, BAS, pool_s, 0, t);
    // ---- CIN layer 2: xk = bufA0+bufA1 on read; single output bufB (RMW) ----
    cin_mfma<K2, H2, 1, HOP2, 6, false, true>(
        x0h, bufA0, bufA1, BAS, wt2, bufB, nullptr, BBS, pool_s, H1, t);
    // bufB = C2 complete; bufA0/A1 dead (red2/Gs alias live from here).

    // ---- layer 3 via Gram: pool3[o] = sum_n G[n] W3[n][o],
    //      G[k][j] = sum_d bufB[d][k] * x0h[d][j]  (exact pooling identity).
    //      Waves 0,1: Gram j-tiles. Waves 2..7: fc1 partials (concurrent). ----
    const int w = t >> 6;
    if (w < 2) {
        const int lane = t & 63, m = lane & 31, h2g = lane >> 5;
        f32x16 g;
        #pragma unroll
        for (int r = 0; r < 16; ++r) g[r] = 0.f;
        #pragma unroll 1
        for (int s = 0; s < 8; ++s) {      // K = 128 d, 16 per MFMA
            us8 a8, b8;
            #pragma unroll
            for (int i = 0; i < 8; ++i) {
                const int d = s * 16 + h2g * 8 + i;
                a8[i] = bufB[d * BBS + m];               // A[k=m][d]
                b8[i] = x0h[d * X0S + w * 32 + m];       // B[d][j=w*32+m]
            }
            g = __builtin_amdgcn_mfma_f32_32x32x16_f16(
                __builtin_bit_cast(half8, a8), __builtin_bit_cast(half8, b8), g, 0, 0, 0);
        }
        #pragma unroll
        for (int r = 0; r < 16; ++r) {
            const int k = (r & 3) + 8 * (r >> 2) + 4 * h2g;
            const int j = w * 32 + m;
            if (j < 48) Gs[k * 48 + j] = g[r];
        }
    } else {
        // fc1 partial (bf16 weights, f16 x0): waves 2..7, 12 parts x 4 fields
        const int tl = t - 128;
        const int u2 = (tl & 31) * 2;
        const int part = tl >> 5;          // 0..11
        float a0 = 0.f, a1 = 0.f;
        for (int j = part * 4; j < part * 4 + 4; ++j) {
            const unsigned short* xr = x0h + j;
            #pragma unroll 4
            for (int d = 0; d < D; ++d) {
                const float xv = hs2f(xr[d * X0S]);
                const unsigned int wp = *(const unsigned int*)(
                    fc1b + ((size_t)j * D + d) * 64 + u2);
                a0 = fmaf(xv, __builtin_bit_cast(float, wp << 16), a0);
                a1 = fmaf(xv, __builtin_bit_cast(float, wp & 0xffff0000u), a1);
            }
        }
        red2[tl * 2]     = a0;
        red2[tl * 2 + 1] = a1;
    }
    __syncthreads();

    // ---- pool3 GEMV (384 thr, contiguous wt3v half8 reads) + h1 combine ----
    if (t < 384) {
        const int o = t % 24, seg = t / 24;   // 16 segs x 96 n's
        const unsigned short* wrow = wt3v + (size_t)o * 1536 + seg * 96;
        const float* gseg = Gs + seg * 96;
        float a = 0.f;
        #pragma unroll 2
        for (int n8 = 0; n8 < 12; ++n8) {
            const us8 wv = *(const us8*)(wrow + n8 * 8);
            #pragma unroll
            for (int i = 0; i < 8; ++i)
                a = fmaf(gseg[n8 * 8 + i], hs2f(wv[i]), a);
        }
        atomicAdd(&pool_s[H1 + H2 + o], a);
    } else if (t < 448) {
        const int uo = t - 384;
        float v = fc1_b[uo];
        #pragma unroll
        for (int p = 0; p < 12; ++p)
            v += red2[(p * 32 + (uo >> 1)) * 2 + (uo & 1)];
        v = fmaxf(v, 0.f);
        h1s[uo] = bn1_g[uo] * v * BN_SCALE + bn1_b[uo];
    }
    __syncthreads();

    if (t < 48) {
        float a = fc2_b[t];
        #pragma unroll 4
        for (int u = 0; u < 64; ++u) a = fmaf(h1s[u], fc2_w[u * 48 + t], a);
        a = tanhf(a);
        h2s[t] = bn2_g[t] * a * BN_SCALE + bn2_b[t];
    }
    __syncthreads();

    if (t < 24) {
        float a = fc3_b[t];
        #pragma unroll 4
        for (int u = 0; u < 48; ++u) a = fmaf(h2s[u], fc3_w[u * 24 + t], a);
        a = tanhf(a);
        h3s[t] = bn3_g[t] * a * BN_SCALE + bn3_b[t];
    }
    __syncthreads();

    if (t == 0) {
        float s = lin_b[0];
        for (int j = 0; j < M; ++j) s += (float)sx[j] * lin_w[j];
        const float slin = tanhf(s);
        float z = out_b[0];
        #pragma unroll 4
        for (int i = 0; i < H3; ++i) z = fmaf(h3s[i], out_w[i], z);
        z = fmaf(slin, out_w[H3], z);
        #pragma unroll 4
        for (int i = 0; i < PO; ++i)
            z = fmaf(pool_s[i], out_w[H3 + 1 + i], z);
        out[b] = 1.f / (1.f + expf(-z));
    }
}

extern "C" void kernel_launch(void* const* d_in, const int* in_sizes, int n_in,
                              void* d_out, int out_size, void* d_ws, size_t ws_size,
                              hipStream_t stream) {
    (void)in_sizes; (void)n_in; (void)ws_size; (void)out_size;
    const int*   x     = (const int*)  d_in[0];
    const float* emb   = (const float*)d_in[1];
    const float* w1    = (const float*)d_in[2];
    const float* w2    = (const float*)d_in[3];
    const float* w3    = (const float*)d_in[4];
    const float* lin_w = (const float*)d_in[5];
    const float* lin_b = (const float*)d_in[6];
    const float* fc1_w = (const float*)d_in[7];
    const float* fc1_b = (const float*)d_in[8];
    const float* bn1_g = (const float*)d_in[9];
    const float* bn1_b = (const float*)d_in[10];
    const float* fc2_w = (const float*)d_in[11];
    const float* fc2_b = (const float*)d_in[12];
    const float* bn2_g = (const float*)d_in[13];
    const float* bn2_b = (const float*)d_in[14];
    const float* fc3_w = (const float*)d_in[15];
    const float* fc3_b = (const float*)d_in[16];
    const float* bn3_g = (const float*)d_in[17];
    const float* bn3_b = (const float*)d_in[18];
    const float* out_w = (const float*)d_in[19];
    const float* out_b = (const float*)d_in[20];
    unsigned short* ws = (unsigned short*)d_ws;

    const int prep_threads = P1 + P2 + P3 + P4 + P5;
    prep_kernel<<<(prep_threads + 255) / 256, 256, 0, stream>>>(w1, w2, w3, fc1_w, ws);

    dcin_kernel<<<512, 512, 0, stream>>>(
        x, emb, ws,
        lin_w, lin_b, fc1_b, bn1_g, bn1_b,
        fc2_w, fc2_b, bn2_g, bn2_b,
        fc3_w, fc3_b, bn3_g, bn3_b,
        out_w, out_b, (float*)d_out);
}